// Round 2
// baseline (396.367 us; speedup 1.0000x reference)
//
#include <hip/hip_runtime.h>
#include <math.h>

#define HW 36864
#define CC 192

typedef __attribute__((ext_vector_type(4))) float f32x4;
typedef __attribute__((ext_vector_type(8))) short bf16x8;

__device__ __forceinline__ float bf2f(unsigned short u) {
    return __uint_as_float(((unsigned int)u) << 16);
}
__device__ __forceinline__ unsigned short f2bf(float f) {
    unsigned int u = __float_as_uint(f);
    unsigned int r = (u + 0x7fffu + ((u >> 16) & 1u)) >> 16;
    return (unsigned short)r;
}

// ---------------------------------------------------------------------------
// Column-persistent GEMM: Out[b][m][n] = sum_k A[b][m][k] * X[b][k][n]
// A: bf16 [M][192] (k contiguous, L2-resident), X: f32/bf16 [192][HW].
// Block stages the FULL 192x128 X column into LDS (transposed, bf16) once,
// then loops over MTILES 64-row m-tiles in groups of MG, loading A fragments
// straight from global (cache-hot). 256 threads, wave owns 32 n-cols.
// ---------------------------------------------------------------------------
template<bool XF32, bool OUTBF, int MTILES, int MG>
__global__ __launch_bounds__(256) void gemm_colp(
    const unsigned short* __restrict__ A,
    const void* __restrict__ Xv,
    void* __restrict__ Outv,
    long aBatchStride, long xBatchStride, long oBatchStride)
{
    const int n0 = blockIdx.x * 128;
    const int b  = blockIdx.y;
    const int tid = threadIdx.x;
    const int lane = tid & 63;
    const int wave = tid >> 6;

    __shared__ __attribute__((aligned(16))) unsigned short Xs[128 * 194]; // [n][k], stride 194

    // ---- stage full X column: 192 x 128 -> Xs[n][k], fp32/bf16 -> bf16 ----
    const int kp = tid & 15;   // k-pair index within 32-k slab
    const int nc = tid >> 4;   // n-chunk of 8
    for (int k0 = 0; k0 < 192; k0 += 32) {
        const int k = k0 + 2 * kp;
        unsigned int pk[8];
        if (XF32) {
            const float* xp = (const float*)Xv + (long)b * xBatchStride + (long)k * HW + n0 + nc * 8;
            float4 a0 = *(const float4*)(xp);
            float4 a1 = *(const float4*)(xp + 4);
            float4 b0 = *(const float4*)(xp + HW);
            float4 b1 = *(const float4*)(xp + HW + 4);
            float lo[8] = {a0.x, a0.y, a0.z, a0.w, a1.x, a1.y, a1.z, a1.w};
            float hi[8] = {b0.x, b0.y, b0.z, b0.w, b1.x, b1.y, b1.z, b1.w};
#pragma unroll
            for (int j = 0; j < 8; ++j)
                pk[j] = (unsigned int)f2bf(lo[j]) | ((unsigned int)f2bf(hi[j]) << 16);
        } else {
            const unsigned short* xp = (const unsigned short*)Xv + (long)b * xBatchStride + (long)k * HW + n0 + nc * 8;
            int4 r0 = *(const int4*)(xp);
            int4 r1 = *(const int4*)(xp + HW);
            const unsigned short* u0 = (const unsigned short*)&r0;
            const unsigned short* u1 = (const unsigned short*)&r1;
#pragma unroll
            for (int j = 0; j < 8; ++j)
                pk[j] = (unsigned int)u0[j] | ((unsigned int)u1[j] << 16);
        }
#pragma unroll
        for (int j = 0; j < 8; ++j)
            *(unsigned int*)&Xs[(nc * 8 + j) * 194 + k] = pk[j];
    }
    __syncthreads();

    const int ml = lane & 15, qk = lane >> 4;
    const unsigned short* Ab = A + (long)b * aBatchStride;

    for (int mg = 0; mg < MTILES; mg += MG) {
        f32x4 acc[MG][4][2];
#pragma unroll
        for (int t = 0; t < MG; ++t)
#pragma unroll
            for (int f = 0; f < 4; ++f)
#pragma unroll
                for (int g = 0; g < 2; ++g)
                    acc[t][f][g] = (f32x4){0.f, 0.f, 0.f, 0.f};

        for (int k0 = 0; k0 < 192; k0 += 32) {
            bf16x8 bfr[2];
#pragma unroll
            for (int g = 0; g < 2; ++g) {
                const unsigned short* p = &Xs[(wave * 32 + g * 16 + ml) * 194 + k0 + qk * 8];
                union { bf16x8 v; unsigned int u[4]; } tmp;
                tmp.u[0] = *(const unsigned int*)(p + 0);
                tmp.u[1] = *(const unsigned int*)(p + 2);
                tmp.u[2] = *(const unsigned int*)(p + 4);
                tmp.u[3] = *(const unsigned int*)(p + 6);
                bfr[g] = tmp.v;
            }
#pragma unroll
            for (int t = 0; t < MG; ++t)
#pragma unroll
                for (int f = 0; f < 4; ++f) {
                    bf16x8 af = *(const bf16x8*)(Ab + (long)((mg + t) * 64 + f * 16 + ml) * 192 + k0 + qk * 8);
                    acc[t][f][0] = __builtin_amdgcn_mfma_f32_16x16x32_bf16(af, bfr[0], acc[t][f][0], 0, 0, 0);
                    acc[t][f][1] = __builtin_amdgcn_mfma_f32_16x16x32_bf16(af, bfr[1], acc[t][f][1], 0, 0, 0);
                }
        }

        // epilogue for this group
#pragma unroll
        for (int t = 0; t < MG; ++t) {
            if (OUTBF) {
                unsigned short* Out = (unsigned short*)Outv + (long)b * oBatchStride;
#pragma unroll
                for (int f = 0; f < 4; ++f)
#pragma unroll
                    for (int g = 0; g < 2; ++g) {
                        const int gm = (mg + t) * 64 + f * 16 + qk * 4;
                        const int gn = n0 + wave * 32 + g * 16 + ml;
#pragma unroll
                        for (int i = 0; i < 4; ++i)
                            Out[(long)(gm + i) * HW + gn] = f2bf(acc[t][f][g][i]);
                    }
            } else {
                float* Out = (float*)Outv + (long)b * oBatchStride;
#pragma unroll
                for (int f = 0; f < 4; ++f)
#pragma unroll
                    for (int g = 0; g < 2; ++g) {
                        const int gm = (mg + t) * 64 + f * 16 + qk * 4;
                        const int gn = n0 + wave * 32 + g * 16 + ml;
#pragma unroll
                        for (int i = 0; i < 4; ++i)
                            Out[(long)(gm + i) * HW + gn] = acc[t][f][g][i];
                    }
            }
        }
    }
}

// ---------------------------------------------------------------------------
// Depthwise 3x3 conv (SAME, zero pad), bf16 in/out, fp32 math.
// Also accumulates per-channel sum-of-squares for q/k channels (ch < 384).
// ---------------------------------------------------------------------------
__global__ __launch_bounds__(256) void dwconv_kernel(
    const unsigned short* __restrict__ qkv,
    const float* __restrict__ wdw,
    unsigned short* __restrict__ dwout,
    float* __restrict__ ssq)
{
    const int ht = blockIdx.x;   // 0..23 (8-row tiles)
    const int ch = blockIdx.y;   // 0..575
    const int b  = blockIdx.z;
    const int tid = threadIdx.x;
    const int h0 = ht * 8;

    __shared__ float s[10 * 194];
    __shared__ float wsm[9];
    __shared__ float red[4];

    if (tid < 9) wsm[tid] = wdw[ch * 9 + tid];
    if (tid < 20) { int r = tid >> 1; int c = (tid & 1) ? 193 : 0; s[r * 194 + c] = 0.f; }

    const long chbase = (long)(b * 576 + ch) * HW;
    for (int idx = tid; idx < 1920; idx += 256) {
        int r = idx / 192, w = idx - r * 192;
        int hh = h0 - 1 + r;
        float v = 0.f;
        if (hh >= 0 && hh < 192) v = bf2f(qkv[chbase + hh * 192 + w]);
        s[r * 194 + 1 + w] = v;
    }
    __syncthreads();

    const float w00 = wsm[0], w01 = wsm[1], w02 = wsm[2];
    const float w10 = wsm[3], w11 = wsm[4], w12 = wsm[5];
    const float w20 = wsm[6], w21 = wsm[7], w22 = wsm[8];

    float mysq = 0.f;
    for (int idx = tid; idx < 1536; idx += 256) {
        int hh = idx / 192, w = idx - hh * 192;
        const float* r0 = &s[hh * 194 + w];
        const float* r1 = r0 + 194;
        const float* r2 = r1 + 194;
        float acc = w00 * r0[0] + w01 * r0[1] + w02 * r0[2]
                  + w10 * r1[0] + w11 * r1[1] + w12 * r1[2]
                  + w20 * r2[0] + w21 * r2[1] + w22 * r2[2];
        dwout[chbase + (h0 + hh) * 192 + w] = f2bf(acc);
        mysq += acc * acc;
    }

    if (ch < 384) {
#pragma unroll
        for (int off = 32; off > 0; off >>= 1) mysq += __shfl_xor(mysq, off, 64);
        if ((tid & 63) == 0) red[tid >> 6] = mysq;
        __syncthreads();
        if (tid == 0) atomicAdd(&ssq[b * 384 + ch], red[0] + red[1] + red[2] + red[3]);
    }
}

// ---------------------------------------------------------------------------
// Gram: gram[b,h,d,e] += sum_n q[d][n]*k[e][n] over a 256-col chunk. MFMA TN.
// ---------------------------------------------------------------------------
__global__ __launch_bounds__(64) void gram_kernel(
    const unsigned short* __restrict__ dwb, float* __restrict__ gram)
{
    const int chunk = blockIdx.x;  // 0..143
    const int bh = blockIdx.y;     // 0..7
    const int b = bh >> 2, h = bh & 3;
    const int lane = threadIdx.x;
    const int row = lane & 15, qk = lane >> 4;
    const long n0 = (long)chunk * 256;

    const unsigned short* qb = dwb + (long)(b * 576 + h * 48) * HW + n0;
    const unsigned short* kb = dwb + (long)(b * 576 + 192 + h * 48) * HW + n0;

    f32x4 acc[3][3];
#pragma unroll
    for (int f = 0; f < 3; ++f)
#pragma unroll
        for (int g = 0; g < 3; ++g) acc[f][g] = (f32x4){0.f, 0.f, 0.f, 0.f};

    for (int kk = 0; kk < 256; kk += 32) {
        const int col = kk + qk * 8;
        bf16x8 aq[3], bk[3];
#pragma unroll
        for (int f = 0; f < 3; ++f) aq[f] = *(const bf16x8*)(qb + (long)(f * 16 + row) * HW + col);
#pragma unroll
        for (int g = 0; g < 3; ++g) bk[g] = *(const bf16x8*)(kb + (long)(g * 16 + row) * HW + col);
#pragma unroll
        for (int f = 0; f < 3; ++f)
#pragma unroll
            for (int g = 0; g < 3; ++g)
                acc[f][g] = __builtin_amdgcn_mfma_f32_16x16x32_bf16(aq[f], bk[g], acc[f][g], 0, 0, 0);
    }

    float* gb = gram + bh * 2304;
#pragma unroll
    for (int f = 0; f < 3; ++f)
#pragma unroll
        for (int g = 0; g < 3; ++g)
#pragma unroll
            for (int i = 0; i < 4; ++i)
                atomicAdd(&gb[(f * 16 + qk * 4 + i) * 48 + g * 16 + row], acc[f][g][i]);
}

// ---------------------------------------------------------------------------
// attn = softmax( gram / (|q_d||k_e|) * softplus(logT) + eps ) over e
// ---------------------------------------------------------------------------
__global__ __launch_bounds__(64) void attn_kernel(
    const float* __restrict__ gram, const float* __restrict__ ssq,
    const float* __restrict__ lt, float* __restrict__ attn)
{
    const int bh = blockIdx.x;
    const int b = bh >> 2, h = bh & 3;
    const int d = threadIdx.x;
    if (d >= 48) return;
    const float temp = log1pf(expf(lt[h])) + 1e-6f;
    const float invq = 1.f / fmaxf(sqrtf(ssq[b * 384 + h * 48 + d]), 1e-12f);
    float p[48];
    float mx = -1e30f;
#pragma unroll
    for (int e = 0; e < 48; ++e) {
        float invk = 1.f / fmaxf(sqrtf(ssq[b * 384 + 192 + h * 48 + e]), 1e-12f);
        float g = gram[bh * 2304 + d * 48 + e] * invq * invk * temp;
        p[e] = g;
        mx = fmaxf(mx, g);
    }
    float sum = 0.f;
#pragma unroll
    for (int e = 0; e < 48; ++e) { float x = expf(p[e] - mx); p[e] = x; sum += x; }
    const float inv = 1.f / sum;
#pragma unroll
    for (int e = 0; e < 48; ++e) attn[bh * 2304 + d * 48 + e] = p[e] * inv;
}

// ---------------------------------------------------------------------------
// M[b][o][h*48+e] = sum_d wproj[o][h*48+d] * attn[b][h][d][e]   (bf16 out)
// ---------------------------------------------------------------------------
__global__ __launch_bounds__(192) void mproj_kernel(
    const float* __restrict__ wproj, const float* __restrict__ attn,
    unsigned short* __restrict__ Mb)
{
    const int o = blockIdx.x;
    const int b = blockIdx.y;
    const int he = threadIdx.x;
    const int h = he / 48, e = he - h * 48;
    const float* ar = attn + ((b * 4 + h) * 48) * 48 + e;
    const float* wr = wproj + o * 192 + h * 48;
    float acc = 0.f;
#pragma unroll
    for (int d = 0; d < 48; ++d) acc += wr[d] * ar[d * 48];
    Mb[(long)(b * 192 + o) * 192 + he] = f2bf(acc);
}

__global__ void cvt_bf16_kernel(const float* __restrict__ in,
                                unsigned short* __restrict__ out, int n)
{
    int i = blockIdx.x * 256 + threadIdx.x;
    if (i < n) out[i] = f2bf(in[i]);
}

// ---------------------------------------------------------------------------
extern "C" void kernel_launch(void* const* d_in, const int* in_sizes, int n_in,
                              void* d_out, int out_size, void* d_ws, size_t ws_size,
                              hipStream_t stream)
{
    const float* x      = (const float*)d_in[0];
    const float* w_qkv  = (const float*)d_in[1];
    const float* w_dw   = (const float*)d_in[2];
    const float* w_proj = (const float*)d_in[3];
    const float* lt     = (const float*)d_in[4];

    char* ws = (char*)d_ws;
    unsigned short* wqkv_b = (unsigned short*)(ws + 0);          // 221184 B
    float* gram            = (float*)(ws + 221184);              // 73728 B
    float* ssq             = (float*)(ws + 294912);              // 3072 B
    float* attn            = (float*)(ws + 297984);              // 73728 B
    unsigned short* Mb     = (unsigned short*)(ws + 371712);     // 147456 B
    unsigned short* qkvb   = (unsigned short*)(ws + 524288);     // 84934656 B
    unsigned short* dwb    = (unsigned short*)(ws + 524288 + 84934656ll);

    // zero the atomic accumulators (gram + ssq are adjacent)
    hipMemsetAsync(gram, 0, 73728 + 3072, stream);

    // w_qkv -> bf16
    cvt_bf16_kernel<<<dim3((110592 + 255) / 256), 256, 0, stream>>>(w_qkv, wqkv_b, 110592);

    // qkv = w_qkv @ x   (M=576, K=192, N=HW per batch) — column-persistent
    gemm_colp<true, true, 9, 3><<<dim3(288, 2), 256, 0, stream>>>(
        wqkv_b, (const void*)x, (void*)qkvb,
        0L, (long)192 * HW, (long)576 * HW);

    // depthwise 3x3 + sumsq(q,k)
    dwconv_kernel<<<dim3(24, 576, 2), 256, 0, stream>>>(qkvb, w_dw, dwb, ssq);

    // gram = q @ k^T per (b, head)
    gram_kernel<<<dim3(144, 8), 64, 0, stream>>>(dwb, gram);

    // softmax(normalized gram * temperature)
    attn_kernel<<<dim3(8), 64, 0, stream>>>(gram, ssq, lt, attn);

    // M = w_proj @ attn (per batch, per head), bf16
    mproj_kernel<<<dim3(192, 2), 192, 0, stream>>>(w_proj, attn, Mb);

    // out = M @ v   (M=192, K=192, N=HW per batch), fp32 out — column-persistent
    gemm_colp<false, false, 3, 3><<<dim3(288, 2), 256, 0, stream>>>(
        Mb, (const void*)(dwb + (long)384 * HW), d_out,
        (long)192 * 192, (long)576 * HW, (long)192 * HW);
}

// Round 3
// 386.952 us; speedup vs baseline: 1.0243x; 1.0243x over previous
//
#include <hip/hip_runtime.h>
#include <math.h>

#define HW 36864
#define CC 192

typedef __attribute__((ext_vector_type(4))) float f32x4;
typedef __attribute__((ext_vector_type(8))) short bf16x8;

__device__ __forceinline__ float bf2f(unsigned short u) {
    return __uint_as_float(((unsigned int)u) << 16);
}
__device__ __forceinline__ unsigned short f2bf(float f) {
    unsigned int u = __float_as_uint(f);
    unsigned int r = (u + 0x7fffu + ((u >> 16) & 1u)) >> 16;
    return (unsigned short)r;
}

// ---------------------------------------------------------------------------
// Column-persistent GEMM, BN=64, m-range split over blockIdx.z.
// Out[b][m][n] = sum_k A[b][m][k] * X[b][k][n]
// A: bf16 [M][192] k-contiguous (L2-hot). X: f32/bf16 [192][HW] n-contiguous.
// Block stages full 192(k) x 64(n) X column into LDS (transposed bf16) once;
// k-loop reads LDS + global A only (no barriers) -> waves run free.
// Grid: (HW/64, batch, M/(MG*64)). 256 thr, wave owns 16 n-cols, MG*64 m-rows.
// ---------------------------------------------------------------------------
template<bool XF32, bool OUTBF, int MG>
__global__ __launch_bounds__(256, 4) void gemm_colp(
    const unsigned short* __restrict__ A,
    const void* __restrict__ Xv,
    void* __restrict__ Outv,
    long aBatchStride, long xBatchStride, long oBatchStride)
{
    const int n0 = blockIdx.x * 64;
    const int b  = blockIdx.y;
    const int mbase = blockIdx.z * (MG * 64);
    const int tid = threadIdx.x;
    const int lane = tid & 63;
    const int wave = tid >> 6;

    // stride 202 shorts = 101 dwords (101 % 32 == 5): <=2-way conflicts
    __shared__ __attribute__((aligned(16))) unsigned short Xs[64 * 202];

    // ---- stage full X column: 192(k) x 64(n) -> Xs[n][k] bf16 ----
    const int kp = tid & 31;   // k-pair within 64-k slab
    const int nc = tid >> 5;   // n-chunk of 8 (0..7)
    for (int k0 = 0; k0 < 192; k0 += 64) {
        const int k = k0 + 2 * kp;
        unsigned int pk[8];
        if (XF32) {
            const float* xp = (const float*)Xv + (long)b * xBatchStride + (long)k * HW + n0 + nc * 8;
            float4 a0 = *(const float4*)(xp);
            float4 a1 = *(const float4*)(xp + 4);
            float4 b0 = *(const float4*)(xp + HW);
            float4 b1 = *(const float4*)(xp + HW + 4);
            float lo[8] = {a0.x, a0.y, a0.z, a0.w, a1.x, a1.y, a1.z, a1.w};
            float hi[8] = {b0.x, b0.y, b0.z, b0.w, b1.x, b1.y, b1.z, b1.w};
#pragma unroll
            for (int j = 0; j < 8; ++j)
                pk[j] = (unsigned int)f2bf(lo[j]) | ((unsigned int)f2bf(hi[j]) << 16);
        } else {
            const unsigned short* xp = (const unsigned short*)Xv + (long)b * xBatchStride + (long)k * HW + n0 + nc * 8;
            int4 r0 = *(const int4*)(xp);
            int4 r1 = *(const int4*)(xp + HW);
            const unsigned short* u0 = (const unsigned short*)&r0;
            const unsigned short* u1 = (const unsigned short*)&r1;
#pragma unroll
            for (int j = 0; j < 8; ++j)
                pk[j] = (unsigned int)u0[j] | ((unsigned int)u1[j] << 16);
        }
#pragma unroll
        for (int j = 0; j < 8; ++j)
            *(unsigned int*)&Xs[(nc * 8 + j) * 202 + k] = pk[j];
    }
    __syncthreads();

    const int ml = lane & 15, qk = lane >> 4;
    const unsigned short* Ab = A + (long)b * aBatchStride;

    f32x4 acc[MG][4];
#pragma unroll
    for (int t = 0; t < MG; ++t)
#pragma unroll
        for (int f = 0; f < 4; ++f)
            acc[t][f] = (f32x4){0.f, 0.f, 0.f, 0.f};

#pragma unroll
    for (int k0 = 0; k0 < 192; k0 += 32) {
        bf16x8 bfr;
        {
            const unsigned short* p = &Xs[(wave * 16 + ml) * 202 + k0 + qk * 8];
            union { bf16x8 v; unsigned int u[4]; } tmp;
            tmp.u[0] = *(const unsigned int*)(p + 0);
            tmp.u[1] = *(const unsigned int*)(p + 2);
            tmp.u[2] = *(const unsigned int*)(p + 4);
            tmp.u[3] = *(const unsigned int*)(p + 6);
            bfr = tmp.v;
        }
#pragma unroll
        for (int t = 0; t < MG; ++t)
#pragma unroll
            for (int f = 0; f < 4; ++f) {
                bf16x8 af = *(const bf16x8*)(Ab + (long)(mbase + t * 64 + f * 16 + ml) * 192 + k0 + qk * 8);
                acc[t][f] = __builtin_amdgcn_mfma_f32_16x16x32_bf16(af, bfr, acc[t][f], 0, 0, 0);
            }
    }

#pragma unroll
    for (int t = 0; t < MG; ++t) {
        if (OUTBF) {
            unsigned short* Out = (unsigned short*)Outv + (long)b * oBatchStride;
#pragma unroll
            for (int f = 0; f < 4; ++f) {
                const int gm = mbase + t * 64 + f * 16 + qk * 4;
                const int gn = n0 + wave * 16 + ml;
#pragma unroll
                for (int i = 0; i < 4; ++i)
                    Out[(long)(gm + i) * HW + gn] = f2bf(acc[t][f][i]);
            }
        } else {
            float* Out = (float*)Outv + (long)b * oBatchStride;
#pragma unroll
            for (int f = 0; f < 4; ++f) {
                const int gm = mbase + t * 64 + f * 16 + qk * 4;
                const int gn = n0 + wave * 16 + ml;
#pragma unroll
                for (int i = 0; i < 4; ++i)
                    Out[(long)(gm + i) * HW + gn] = acc[t][f][i];
            }
        }
    }
}

// ---------------------------------------------------------------------------
// Depthwise 3x3 conv (SAME, zero pad), LDS-free, int4-vectorized.
// 32 lanes per output row (24 active, 8 px each); horizontal halo via __shfl
// within the 32-lane group; vertical halo via redundant row loads (L1-hot).
// Also accumulates per-channel sum-of-squares for q/k channels (ch < 384).
// ---------------------------------------------------------------------------
__global__ __launch_bounds__(256) void dwconv_kernel(
    const unsigned short* __restrict__ qkv,
    const float* __restrict__ wdw,
    unsigned short* __restrict__ dwout,
    float* __restrict__ ssq)
{
    const int ht = blockIdx.x;   // 0..23 (8-row tiles)
    const int ch = blockIdx.y;   // 0..575
    const int b  = blockIdx.z;
    const int tid = threadIdx.x;
    const int lane = tid & 63;
    const int h0 = ht * 8;
    const int t  = tid & 31;     // lane in row group; 0..23 active
    const int hh = tid >> 5;     // 0..7 output row within tile
    const bool active = (t < 24);

    const float* wp = wdw + ch * 9;
    const float w00 = wp[0], w01 = wp[1], w02 = wp[2];
    const float w10 = wp[3], w11 = wp[4], w12 = wp[5];
    const float w20 = wp[6], w21 = wp[7], w22 = wp[8];

    const long chbase = (long)(b * 576 + ch) * HW;

    float x[3][8];
#pragma unroll
    for (int dy = 0; dy < 3; ++dy) {
        const int hr = h0 + hh + dy - 1;
        int4 ld = make_int4(0, 0, 0, 0);
        if (active && hr >= 0 && hr < 192)
            ld = *(const int4*)(qkv + chbase + (long)hr * 192 + t * 8);
        const unsigned short* u = (const unsigned short*)&ld;
#pragma unroll
        for (int j = 0; j < 8; ++j) x[dy][j] = bf2f(u[j]);
    }

    float lft[3], rgt[3];
#pragma unroll
    for (int dy = 0; dy < 3; ++dy) {
        float l = __shfl(x[dy][7], lane - 1, 64);
        float r = __shfl(x[dy][0], lane + 1, 64);
        lft[dy] = (t == 0) ? 0.f : l;
        rgt[dy] = (t >= 23) ? 0.f : r;
    }

    float acc[8];
#pragma unroll
    for (int j = 0; j < 8; ++j) {
        float a0 = (j == 0) ? lft[0] : x[0][j - 1];
        float a2 = (j == 7) ? rgt[0] : x[0][j + 1];
        float b0 = (j == 0) ? lft[1] : x[1][j - 1];
        float b2 = (j == 7) ? rgt[1] : x[1][j + 1];
        float c0 = (j == 0) ? lft[2] : x[2][j - 1];
        float c2 = (j == 7) ? rgt[2] : x[2][j + 1];
        acc[j] = w00 * a0 + w01 * x[0][j] + w02 * a2
               + w10 * b0 + w11 * x[1][j] + w12 * b2
               + w20 * c0 + w21 * x[2][j] + w22 * c2;
    }

    if (active) {
        int4 st;
        unsigned short* u = (unsigned short*)&st;
#pragma unroll
        for (int j = 0; j < 8; ++j) u[j] = f2bf(acc[j]);
        *(int4*)(dwout + chbase + (long)(h0 + hh) * 192 + t * 8) = st;
    }

    if (ch < 384) {
        float mysq = 0.f;
        if (active) {
#pragma unroll
            for (int j = 0; j < 8; ++j) mysq += acc[j] * acc[j];
        }
#pragma unroll
        for (int off = 32; off > 0; off >>= 1) mysq += __shfl_xor(mysq, off, 64);
        __shared__ float red[4];
        if (lane == 0) red[tid >> 6] = mysq;
        __syncthreads();
        if (tid == 0) atomicAdd(&ssq[b * 384 + ch], red[0] + red[1] + red[2] + red[3]);
    }
}

// ---------------------------------------------------------------------------
// Gram: gram[b,h,d,e] += sum_n q[d][n]*k[e][n] over a 512-col chunk. MFMA TN.
// ---------------------------------------------------------------------------
__global__ __launch_bounds__(64) void gram_kernel(
    const unsigned short* __restrict__ dwb, float* __restrict__ gram)
{
    const int chunk = blockIdx.x;  // 0..71
    const int bh = blockIdx.y;     // 0..7
    const int b = bh >> 2, h = bh & 3;
    const int lane = threadIdx.x;
    const int row = lane & 15, qk = lane >> 4;
    const long n0 = (long)chunk * 512;

    const unsigned short* qb = dwb + (long)(b * 576 + h * 48) * HW + n0;
    const unsigned short* kb = dwb + (long)(b * 576 + 192 + h * 48) * HW + n0;

    f32x4 acc[3][3];
#pragma unroll
    for (int f = 0; f < 3; ++f)
#pragma unroll
        for (int g = 0; g < 3; ++g) acc[f][g] = (f32x4){0.f, 0.f, 0.f, 0.f};

    for (int kk = 0; kk < 512; kk += 32) {
        const int col = kk + qk * 8;
        bf16x8 aq[3], bk[3];
#pragma unroll
        for (int f = 0; f < 3; ++f) aq[f] = *(const bf16x8*)(qb + (long)(f * 16 + row) * HW + col);
#pragma unroll
        for (int g = 0; g < 3; ++g) bk[g] = *(const bf16x8*)(kb + (long)(g * 16 + row) * HW + col);
#pragma unroll
        for (int f = 0; f < 3; ++f)
#pragma unroll
            for (int g = 0; g < 3; ++g)
                acc[f][g] = __builtin_amdgcn_mfma_f32_16x16x32_bf16(aq[f], bk[g], acc[f][g], 0, 0, 0);
    }

    float* gb = gram + bh * 2304;
#pragma unroll
    for (int f = 0; f < 3; ++f)
#pragma unroll
        for (int g = 0; g < 3; ++g)
#pragma unroll
            for (int i = 0; i < 4; ++i)
                atomicAdd(&gb[(f * 16 + qk * 4 + i) * 48 + g * 16 + row], acc[f][g][i]);
}

// ---------------------------------------------------------------------------
// attn = softmax( gram / (|q_d||k_e|) * softplus(logT) + eps ) over e
// ---------------------------------------------------------------------------
__global__ __launch_bounds__(64) void attn_kernel(
    const float* __restrict__ gram, const float* __restrict__ ssq,
    const float* __restrict__ lt, float* __restrict__ attn)
{
    const int bh = blockIdx.x;
    const int b = bh >> 2, h = bh & 3;
    const int d = threadIdx.x;
    if (d >= 48) return;
    const float temp = log1pf(expf(lt[h])) + 1e-6f;
    const float invq = 1.f / fmaxf(sqrtf(ssq[b * 384 + h * 48 + d]), 1e-12f);
    float p[48];
    float mx = -1e30f;
#pragma unroll
    for (int e = 0; e < 48; ++e) {
        float invk = 1.f / fmaxf(sqrtf(ssq[b * 384 + 192 + h * 48 + e]), 1e-12f);
        float g = gram[bh * 2304 + d * 48 + e] * invq * invk * temp;
        p[e] = g;
        mx = fmaxf(mx, g);
    }
    float sum = 0.f;
#pragma unroll
    for (int e = 0; e < 48; ++e) { float x = expf(p[e] - mx); p[e] = x; sum += x; }
    const float inv = 1.f / sum;
#pragma unroll
    for (int e = 0; e < 48; ++e) attn[bh * 2304 + d * 48 + e] = p[e] * inv;
}

// ---------------------------------------------------------------------------
// M[b][o][h*48+e] = sum_d wproj[o][h*48+d] * attn[b][h][d][e]   (bf16 out)
// ---------------------------------------------------------------------------
__global__ __launch_bounds__(192) void mproj_kernel(
    const float* __restrict__ wproj, const float* __restrict__ attn,
    unsigned short* __restrict__ Mb)
{
    const int o = blockIdx.x;
    const int b = blockIdx.y;
    const int he = threadIdx.x;
    const int h = he / 48, e = he - h * 48;
    const float* ar = attn + ((b * 4 + h) * 48) * 48 + e;
    const float* wr = wproj + o * 192 + h * 48;
    float acc = 0.f;
#pragma unroll
    for (int d = 0; d < 48; ++d) acc += wr[d] * ar[d * 48];
    Mb[(long)(b * 192 + o) * 192 + he] = f2bf(acc);
}

__global__ void cvt_bf16_kernel(const float* __restrict__ in,
                                unsigned short* __restrict__ out, int n)
{
    int i = blockIdx.x * 256 + threadIdx.x;
    if (i < n) out[i] = f2bf(in[i]);
}

// ---------------------------------------------------------------------------
extern "C" void kernel_launch(void* const* d_in, const int* in_sizes, int n_in,
                              void* d_out, int out_size, void* d_ws, size_t ws_size,
                              hipStream_t stream)
{
    const float* x      = (const float*)d_in[0];
    const float* w_qkv  = (const float*)d_in[1];
    const float* w_dw   = (const float*)d_in[2];
    const float* w_proj = (const float*)d_in[3];
    const float* lt     = (const float*)d_in[4];

    char* ws = (char*)d_ws;
    unsigned short* wqkv_b = (unsigned short*)(ws + 0);          // 221184 B
    float* gram            = (float*)(ws + 221184);              // 73728 B
    float* ssq             = (float*)(ws + 294912);              // 3072 B
    float* attn            = (float*)(ws + 297984);              // 73728 B
    unsigned short* Mb     = (unsigned short*)(ws + 371712);     // 147456 B
    unsigned short* qkvb   = (unsigned short*)(ws + 524288);     // 84934656 B
    unsigned short* dwb    = (unsigned short*)(ws + 524288 + 84934656ll);

    // zero the atomic accumulators (gram + ssq are adjacent)
    hipMemsetAsync(gram, 0, 73728 + 3072, stream);

    // w_qkv -> bf16
    cvt_bf16_kernel<<<dim3((110592 + 255) / 256), 256, 0, stream>>>(w_qkv, wqkv_b, 110592);

    // qkv = w_qkv @ x  (M=576, K=192, N=HW per batch): 576 n-tiles x 2 b x 3 m-groups
    gemm_colp<true, true, 3><<<dim3(576, 2, 3), 256, 0, stream>>>(
        wqkv_b, (const void*)x, (void*)qkvb,
        0L, (long)192 * HW, (long)576 * HW);

    // depthwise 3x3 + sumsq(q,k)
    dwconv_kernel<<<dim3(24, 576, 2), 256, 0, stream>>>(qkvb, w_dw, dwb, ssq);

    // gram = q @ k^T per (b, head)
    gram_kernel<<<dim3(72, 8), 64, 0, stream>>>(dwb, gram);

    // softmax(normalized gram * temperature)
    attn_kernel<<<dim3(8), 64, 0, stream>>>(gram, ssq, lt, attn);

    // M = w_proj @ attn (per batch, per head), bf16
    mproj_kernel<<<dim3(192, 2), 192, 0, stream>>>(w_proj, attn, Mb);

    // out = M @ v  (M=192, K=192, N=HW per batch), fp32 out
    gemm_colp<false, false, 3><<<dim3(576, 2, 1), 256, 0, stream>>>(
        Mb, (const void*)(dwb + (long)384 * HW), d_out,
        (long)192 * 192, (long)576 * HW, (long)192 * HW);
}

// Round 4
// 269.066 us; speedup vs baseline: 1.4731x; 1.4381x over previous
//
#include <hip/hip_runtime.h>
#include <math.h>

#define HW 36864
#define CC 192

typedef __attribute__((ext_vector_type(4))) float f32x4;
typedef __attribute__((ext_vector_type(8))) short bf16x8;

__device__ __forceinline__ float bf2f(unsigned short u) {
    return __uint_as_float(((unsigned int)u) << 16);
}
__device__ __forceinline__ unsigned short f2bf(float f) {
    unsigned int u = __float_as_uint(f);
    unsigned int r = (u + 0x7fffu + ((u >> 16) & 1u)) >> 16;
    return (unsigned short)r;
}

// ---------------------------------------------------------------------------
// Register-persistent-A column GEMM.
// Out[b][m][n] = sum_k A[b][m][k] * X[b][k][n]
// A: bf16 [M][192] k-contiguous (L1/L2-hot). X: f32/bf16 [192][HW].
// Block = 4 waves = 192 m-rows (one z-group) x 64 n. Each wave holds its
// 48-row A slice in registers (18 frags = 72 VGPRs), loaded ONCE. X column
// (192k x 64n) staged to LDS (transposed bf16) once. The compute loop is
// pure LDS + MFMA: 24 ds_read_b128, 72 mfma per wave. No global loads.
// Grid: (HW/64, batch, M/192).
// ---------------------------------------------------------------------------
template<bool XF32, bool OUTBF>
__global__ __launch_bounds__(256, 3) void gemm_rpa(
    const unsigned short* __restrict__ A,
    const void* __restrict__ Xv,
    void* __restrict__ Outv,
    long aBatchStride, long xBatchStride, long oBatchStride)
{
    const int n0 = blockIdx.x * 64;
    const int b  = blockIdx.y;
    const int mbase = blockIdx.z * 192;
    const int tid = threadIdx.x;
    const int lane = tid & 63;
    const int wave = tid >> 6;
    const int ml = lane & 15, qk = lane >> 4;

    // stride 202 shorts = 101 dwords (101 % 32 == 5): <=2-way conflicts
    __shared__ __attribute__((aligned(16))) unsigned short Xs[64 * 202];

    // ---- A fragments: 48 rows x 192 k per wave, loaded once ----
    const unsigned short* Ab = A + (long)b * aBatchStride;
    bf16x8 afr[3][6];
#pragma unroll
    for (int f = 0; f < 3; ++f) {
        const unsigned short* row = Ab + (long)(mbase + wave * 48 + f * 16 + ml) * 192 + qk * 8;
#pragma unroll
        for (int kk = 0; kk < 6; ++kk)
            afr[f][kk] = *(const bf16x8*)(row + kk * 32);
    }

    // ---- stage full X column: 192(k) x 64(n) -> Xs[n][k] bf16 ----
    const int kp = tid & 31;   // k-pair within 64-k slab
    const int nc = tid >> 5;   // n-chunk of 8 (0..7)
    for (int k0 = 0; k0 < 192; k0 += 64) {
        const int k = k0 + 2 * kp;
        unsigned int pk[8];
        if (XF32) {
            const float* xp = (const float*)Xv + (long)b * xBatchStride + (long)k * HW + n0 + nc * 8;
            float4 a0 = *(const float4*)(xp);
            float4 a1 = *(const float4*)(xp + 4);
            float4 b0 = *(const float4*)(xp + HW);
            float4 b1 = *(const float4*)(xp + HW + 4);
            float lo[8] = {a0.x, a0.y, a0.z, a0.w, a1.x, a1.y, a1.z, a1.w};
            float hi[8] = {b0.x, b0.y, b0.z, b0.w, b1.x, b1.y, b1.z, b1.w};
#pragma unroll
            for (int j = 0; j < 8; ++j)
                pk[j] = (unsigned int)f2bf(lo[j]) | ((unsigned int)f2bf(hi[j]) << 16);
        } else {
            const unsigned short* xp = (const unsigned short*)Xv + (long)b * xBatchStride + (long)k * HW + n0 + nc * 8;
            int4 r0 = *(const int4*)(xp);
            int4 r1 = *(const int4*)(xp + HW);
            const unsigned short* u0 = (const unsigned short*)&r0;
            const unsigned short* u1 = (const unsigned short*)&r1;
#pragma unroll
            for (int j = 0; j < 8; ++j)
                pk[j] = (unsigned int)u0[j] | ((unsigned int)u1[j] << 16);
        }
#pragma unroll
        for (int j = 0; j < 8; ++j)
            *(unsigned int*)&Xs[(nc * 8 + j) * 202 + k] = pk[j];
    }
    __syncthreads();

    // ---- compute: pure LDS + MFMA ----
    f32x4 acc[3][4];  // [m-frag][n-subtile]
#pragma unroll
    for (int f = 0; f < 3; ++f)
#pragma unroll
        for (int s = 0; s < 4; ++s)
            acc[f][s] = (f32x4){0.f, 0.f, 0.f, 0.f};

#pragma unroll
    for (int s = 0; s < 4; ++s) {
#pragma unroll
        for (int kk = 0; kk < 6; ++kk) {
            bf16x8 bfr;
            {
                const unsigned short* p = &Xs[(s * 16 + ml) * 202 + kk * 32 + qk * 8];
                union { bf16x8 v; unsigned int u[4]; } tmp;
                tmp.u[0] = *(const unsigned int*)(p + 0);
                tmp.u[1] = *(const unsigned int*)(p + 2);
                tmp.u[2] = *(const unsigned int*)(p + 4);
                tmp.u[3] = *(const unsigned int*)(p + 6);
                bfr = tmp.v;
            }
#pragma unroll
            for (int f = 0; f < 3; ++f)
                acc[f][s] = __builtin_amdgcn_mfma_f32_16x16x32_bf16(afr[f][kk], bfr, acc[f][s], 0, 0, 0);
        }
    }

    // ---- epilogue ----
#pragma unroll
    for (int f = 0; f < 3; ++f) {
        if (OUTBF) {
            unsigned short* Out = (unsigned short*)Outv + (long)b * oBatchStride;
#pragma unroll
            for (int s = 0; s < 4; ++s) {
                const int gm = mbase + wave * 48 + f * 16 + qk * 4;
                const int gn = n0 + s * 16 + ml;
#pragma unroll
                for (int i = 0; i < 4; ++i)
                    Out[(long)(gm + i) * HW + gn] = f2bf(acc[f][s][i]);
            }
        } else {
            float* Out = (float*)Outv + (long)b * oBatchStride;
#pragma unroll
            for (int s = 0; s < 4; ++s) {
                const int gm = mbase + wave * 48 + f * 16 + qk * 4;
                const int gn = n0 + s * 16 + ml;
#pragma unroll
                for (int i = 0; i < 4; ++i)
                    Out[(long)(gm + i) * HW + gn] = acc[f][s][i];
            }
        }
    }
}

// ---------------------------------------------------------------------------
// Depthwise 3x3 conv (SAME, zero pad), LDS-free, int4-vectorized.
// 32 lanes per output row (24 active, 8 px each); horizontal halo via __shfl
// within the 32-lane group; vertical halo via redundant row loads (L1-hot).
// Also accumulates per-channel sum-of-squares for q/k channels (ch < 384).
// ---------------------------------------------------------------------------
__global__ __launch_bounds__(256) void dwconv_kernel(
    const unsigned short* __restrict__ qkv,
    const float* __restrict__ wdw,
    unsigned short* __restrict__ dwout,
    float* __restrict__ ssq)
{
    const int ht = blockIdx.x;   // 0..23 (8-row tiles)
    const int ch = blockIdx.y;   // 0..575
    const int b  = blockIdx.z;
    const int tid = threadIdx.x;
    const int lane = tid & 63;
    const int h0 = ht * 8;
    const int t  = tid & 31;     // lane in row group; 0..23 active
    const int hh = tid >> 5;     // 0..7 output row within tile
    const bool active = (t < 24);

    const float* wp = wdw + ch * 9;
    const float w00 = wp[0], w01 = wp[1], w02 = wp[2];
    const float w10 = wp[3], w11 = wp[4], w12 = wp[5];
    const float w20 = wp[6], w21 = wp[7], w22 = wp[8];

    const long chbase = (long)(b * 576 + ch) * HW;

    float x[3][8];
#pragma unroll
    for (int dy = 0; dy < 3; ++dy) {
        const int hr = h0 + hh + dy - 1;
        int4 ld = make_int4(0, 0, 0, 0);
        if (active && hr >= 0 && hr < 192)
            ld = *(const int4*)(qkv + chbase + (long)hr * 192 + t * 8);
        const unsigned short* u = (const unsigned short*)&ld;
#pragma unroll
        for (int j = 0; j < 8; ++j) x[dy][j] = bf2f(u[j]);
    }

    float lft[3], rgt[3];
#pragma unroll
    for (int dy = 0; dy < 3; ++dy) {
        float l = __shfl(x[dy][7], lane - 1, 64);
        float r = __shfl(x[dy][0], lane + 1, 64);
        lft[dy] = (t == 0) ? 0.f : l;
        rgt[dy] = (t >= 23) ? 0.f : r;
    }

    float acc[8];
#pragma unroll
    for (int j = 0; j < 8; ++j) {
        float a0 = (j == 0) ? lft[0] : x[0][j - 1];
        float a2 = (j == 7) ? rgt[0] : x[0][j + 1];
        float b0 = (j == 0) ? lft[1] : x[1][j - 1];
        float b2 = (j == 7) ? rgt[1] : x[1][j + 1];
        float c0 = (j == 0) ? lft[2] : x[2][j - 1];
        float c2 = (j == 7) ? rgt[2] : x[2][j + 1];
        acc[j] = w00 * a0 + w01 * x[0][j] + w02 * a2
               + w10 * b0 + w11 * x[1][j] + w12 * b2
               + w20 * c0 + w21 * x[2][j] + w22 * c2;
    }

    if (active) {
        int4 st;
        unsigned short* u = (unsigned short*)&st;
#pragma unroll
        for (int j = 0; j < 8; ++j) u[j] = f2bf(acc[j]);
        *(int4*)(dwout + chbase + (long)(h0 + hh) * 192 + t * 8) = st;
    }

    if (ch < 384) {
        float mysq = 0.f;
        if (active) {
#pragma unroll
            for (int j = 0; j < 8; ++j) mysq += acc[j] * acc[j];
        }
#pragma unroll
        for (int off = 32; off > 0; off >>= 1) mysq += __shfl_xor(mysq, off, 64);
        __shared__ float red[4];
        if (lane == 0) red[tid >> 6] = mysq;
        __syncthreads();
        if (tid == 0) atomicAdd(&ssq[b * 384 + ch], red[0] + red[1] + red[2] + red[3]);
    }
}

// ---------------------------------------------------------------------------
// Gram: gram[b,h,d,e] += sum_n q[d][n]*k[e][n] over a 512-col chunk. MFMA TN.
// ---------------------------------------------------------------------------
__global__ __launch_bounds__(64) void gram_kernel(
    const unsigned short* __restrict__ dwb, float* __restrict__ gram)
{
    const int chunk = blockIdx.x;  // 0..71
    const int bh = blockIdx.y;     // 0..7
    const int b = bh >> 2, h = bh & 3;
    const int lane = threadIdx.x;
    const int row = lane & 15, qk = lane >> 4;
    const long n0 = (long)chunk * 512;

    const unsigned short* qb = dwb + (long)(b * 576 + h * 48) * HW + n0;
    const unsigned short* kb = dwb + (long)(b * 576 + 192 + h * 48) * HW + n0;

    f32x4 acc[3][3];
#pragma unroll
    for (int f = 0; f < 3; ++f)
#pragma unroll
        for (int g = 0; g < 3; ++g) acc[f][g] = (f32x4){0.f, 0.f, 0.f, 0.f};

    for (int kk = 0; kk < 512; kk += 32) {
        const int col = kk + qk * 8;
        bf16x8 aq[3], bk[3];
#pragma unroll
        for (int f = 0; f < 3; ++f) aq[f] = *(const bf16x8*)(qb + (long)(f * 16 + row) * HW + col);
#pragma unroll
        for (int g = 0; g < 3; ++g) bk[g] = *(const bf16x8*)(kb + (long)(g * 16 + row) * HW + col);
#pragma unroll
        for (int f = 0; f < 3; ++f)
#pragma unroll
            for (int g = 0; g < 3; ++g)
                acc[f][g] = __builtin_amdgcn_mfma_f32_16x16x32_bf16(aq[f], bk[g], acc[f][g], 0, 0, 0);
    }

    float* gb = gram + bh * 2304;
#pragma unroll
    for (int f = 0; f < 3; ++f)
#pragma unroll
        for (int g = 0; g < 3; ++g)
#pragma unroll
            for (int i = 0; i < 4; ++i)
                atomicAdd(&gb[(f * 16 + qk * 4 + i) * 48 + g * 16 + row], acc[f][g][i]);
}

// ---------------------------------------------------------------------------
// attn = softmax( gram / (|q_d||k_e|) * softplus(logT) + eps ) over e
// ---------------------------------------------------------------------------
__global__ __launch_bounds__(64) void attn_kernel(
    const float* __restrict__ gram, const float* __restrict__ ssq,
    const float* __restrict__ lt, float* __restrict__ attn)
{
    const int bh = blockIdx.x;
    const int b = bh >> 2, h = bh & 3;
    const int d = threadIdx.x;
    if (d >= 48) return;
    const float temp = log1pf(expf(lt[h])) + 1e-6f;
    const float invq = 1.f / fmaxf(sqrtf(ssq[b * 384 + h * 48 + d]), 1e-12f);
    float p[48];
    float mx = -1e30f;
#pragma unroll
    for (int e = 0; e < 48; ++e) {
        float invk = 1.f / fmaxf(sqrtf(ssq[b * 384 + 192 + h * 48 + e]), 1e-12f);
        float g = gram[bh * 2304 + d * 48 + e] * invq * invk * temp;
        p[e] = g;
        mx = fmaxf(mx, g);
    }
    float sum = 0.f;
#pragma unroll
    for (int e = 0; e < 48; ++e) { float x = expf(p[e] - mx); p[e] = x; sum += x; }
    const float inv = 1.f / sum;
#pragma unroll
    for (int e = 0; e < 48; ++e) attn[bh * 2304 + d * 48 + e] = p[e] * inv;
}

// ---------------------------------------------------------------------------
// M[b][o][h*48+e] = sum_d wproj[o][h*48+d] * attn[b][h][d][e]   (bf16 out)
// ---------------------------------------------------------------------------
__global__ __launch_bounds__(192) void mproj_kernel(
    const float* __restrict__ wproj, const float* __restrict__ attn,
    unsigned short* __restrict__ Mb)
{
    const int o = blockIdx.x;
    const int b = blockIdx.y;
    const int he = threadIdx.x;
    const int h = he / 48, e = he - h * 48;
    const float* ar = attn + ((b * 4 + h) * 48) * 48 + e;
    const float* wr = wproj + o * 192 + h * 48;
    float acc = 0.f;
#pragma unroll
    for (int d = 0; d < 48; ++d) acc += wr[d] * ar[d * 48];
    Mb[(long)(b * 192 + o) * 192 + he] = f2bf(acc);
}

__global__ void cvt_bf16_kernel(const float* __restrict__ in,
                                unsigned short* __restrict__ out, int n)
{
    int i = blockIdx.x * 256 + threadIdx.x;
    if (i < n) out[i] = f2bf(in[i]);
}

// ---------------------------------------------------------------------------
extern "C" void kernel_launch(void* const* d_in, const int* in_sizes, int n_in,
                              void* d_out, int out_size, void* d_ws, size_t ws_size,
                              hipStream_t stream)
{
    const float* x      = (const float*)d_in[0];
    const float* w_qkv  = (const float*)d_in[1];
    const float* w_dw   = (const float*)d_in[2];
    const float* w_proj = (const float*)d_in[3];
    const float* lt     = (const float*)d_in[4];

    char* ws = (char*)d_ws;
    unsigned short* wqkv_b = (unsigned short*)(ws + 0);          // 221184 B
    float* gram            = (float*)(ws + 221184);              // 73728 B
    float* ssq             = (float*)(ws + 294912);              // 3072 B
    float* attn            = (float*)(ws + 297984);              // 73728 B
    unsigned short* Mb     = (unsigned short*)(ws + 371712);     // 147456 B
    unsigned short* qkvb   = (unsigned short*)(ws + 524288);     // 84934656 B
    unsigned short* dwb    = (unsigned short*)(ws + 524288 + 84934656ll);

    // zero the atomic accumulators (gram + ssq are adjacent)
    hipMemsetAsync(gram, 0, 73728 + 3072, stream);

    // w_qkv -> bf16
    cvt_bf16_kernel<<<dim3((110592 + 255) / 256), 256, 0, stream>>>(w_qkv, wqkv_b, 110592);

    // qkv = w_qkv @ x  (M=576, K=192, N=HW per batch): 576 n-tiles x 2 b x 3 m-groups
    gemm_rpa<true, true><<<dim3(576, 2, 3), 256, 0, stream>>>(
        wqkv_b, (const void*)x, (void*)qkvb,
        0L, (long)192 * HW, (long)576 * HW);

    // depthwise 3x3 + sumsq(q,k)
    dwconv_kernel<<<dim3(24, 576, 2), 256, 0, stream>>>(qkvb, w_dw, dwb, ssq);

    // gram = q @ k^T per (b, head)
    gram_kernel<<<dim3(72, 8), 64, 0, stream>>>(dwb, gram);

    // softmax(normalized gram * temperature)
    attn_kernel<<<dim3(8), 64, 0, stream>>>(gram, ssq, lt, attn);

    // M = w_proj @ attn (per batch, per head), bf16
    mproj_kernel<<<dim3(192, 2), 192, 0, stream>>>(w_proj, attn, Mb);

    // out = M @ v  (M=192, K=192, N=HW per batch), fp32 out
    gemm_rpa<false, false><<<dim3(576, 2, 1), 256, 0, stream>>>(
        Mb, (const void*)(dwb + (long)384 * HW), d_out,
        (long)192 * 192, (long)576 * HW, (long)192 * HW);
}